// Round 2
// baseline (1192.810 us; speedup 1.0000x reference)
//
#include <hip/hip_runtime.h>
#include <hip/hip_bf16.h>

#define H 768
#define I_DIM 3072
#define NEXP 16
#define TOPK 2

typedef __bf16 bf16;
typedef __bf16 bf16x4 __attribute__((ext_vector_type(4)));
typedef __bf16 bf16x8 __attribute__((ext_vector_type(8)));
typedef float f32x4 __attribute__((ext_vector_type(4)));

#define MATEL ((size_t)I_DIM * H)

// XCD-affinity swizzle: with gridDim.x % 8 == 0, linear dispatch maps block->XCD as
// bx % 8. Remap so each XCD owns gridX/8 CONSECUTIVE m-tiles -> blocks sharing an
// expert's weight slice co-locate on one XCD's L2.
__device__ __forceinline__ int swizzle_mtile(int bx, int gx) {
    int per = gx >> 3;
    if ((per << 3) != gx) return bx;
    return (bx & 7) * per + (bx >> 3);
}

// ---------------- x -> bf16 ----------------
__global__ void cvt_x_kernel(const float* __restrict__ x, bf16* __restrict__ xb, int n) {
    int i = (blockIdx.x * blockDim.x + threadIdx.x) * 8;
    if (i >= n) return;
    f32x4 v0 = *(const f32x4*)(x + i);
    f32x4 v1 = *(const f32x4*)(x + i + 4);
    bf16x8 p;
#pragma unroll
    for (int j = 0; j < 4; j++) { p[j] = (bf16)v0[j]; p[4 + j] = (bf16)v1[j]; }
    *(bf16x8*)(xb + i) = p;
}

// ---------------- weight transpose + cvt: f32 [R][C] -> bf16 [C][R] ----------------
// 64x64 tile per block. Coalesced f32x4 in, bf16x8 out.
__device__ __forceinline__ void transpose_tile(const float* __restrict__ ip,
                                               bf16* __restrict__ op, int R, int C) {
    __shared__ bf16 t[64][74];  // stride 74 bf16 = 37 words: breaks 16-row bank cycle
    int c0 = blockIdx.x * 64, r0 = blockIdx.y * 64;
    int tid = threadIdx.x;
    int lr = tid >> 4, lc = (tid & 15) * 4;
#pragma unroll
    for (int p = 0; p < 4; p++) {
        int r = p * 16 + lr;
        f32x4 v = *(const f32x4*)(ip + (size_t)(r0 + r) * C + (c0 + lc));
        bf16x4 b;
#pragma unroll
        for (int j = 0; j < 4; j++) b[j] = (bf16)v[j];
        *(bf16x4*)&t[r][lc] = b;
    }
    __syncthreads();
    int oc = tid >> 2, s = (tid & 3) * 16;
    bf16x8 o0, o1;
#pragma unroll
    for (int j = 0; j < 8; j++) { o0[j] = t[s + j][oc]; o1[j] = t[s + 8 + j][oc]; }
    *(bf16x8*)(op + (size_t)(c0 + oc) * R + (r0 + s)) = o0;
    *(bf16x8*)(op + (size_t)(c0 + oc) * R + (r0 + s + 8)) = o1;
}

// gate+up: 36 mats in one dispatch. z: 0..1 swg, 2..17 wg, 18..19 swu, 20..35 wu.
__global__ __launch_bounds__(256) void transpose_gu_kernel(
        const float* __restrict__ swg, const float* __restrict__ wg,
        const float* __restrict__ swu, const float* __restrict__ wu,
        bf16* __restrict__ WgT, bf16* __restrict__ WuT) {
    int z = blockIdx.z;
    const float* src; bf16* dst;
    if (z < 2)       { src = swg + (size_t)z * MATEL;        dst = WgT + (size_t)z * MATEL; }
    else if (z < 18) { src = wg  + (size_t)(z - 2) * MATEL;  dst = WgT + (size_t)z * MATEL; }
    else if (z < 20) { src = swu + (size_t)(z - 18) * MATEL; dst = WuT + (size_t)(z - 18) * MATEL; }
    else             { src = wu  + (size_t)(z - 20) * MATEL; dst = WuT + (size_t)(z - 18) * MATEL; }
    transpose_tile(src, dst, H, I_DIM);
}

// down: 18 mats in one dispatch. z: 0..1 swd, 2..17 wd.
__global__ __launch_bounds__(256) void transpose_d_kernel(
        const float* __restrict__ swd, const float* __restrict__ wd, bf16* __restrict__ WdT) {
    int z = blockIdx.z;
    const float* src; bf16* dst;
    if (z < 2) { src = swd + (size_t)z * MATEL;       dst = WdT + (size_t)z * MATEL; }
    else       { src = wd  + (size_t)(z - 2) * MATEL; dst = WdT + (size_t)z * MATEL; }
    transpose_tile(src, dst, I_DIM, H);
}

// ---------------- router ----------------
__global__ void router_kernel(const float* __restrict__ x, const float* __restrict__ gw,
                              int* __restrict__ tk_e, float* __restrict__ tk_w,
                              int* __restrict__ counts, int N) {
    int wave = threadIdx.x >> 6;
    int lane = threadIdx.x & 63;
    int t = blockIdx.x * 4 + wave;
    if (t >= N) return;
    const float* xr = x + (size_t)t * H;
    float acc[NEXP];
#pragma unroll
    for (int e = 0; e < NEXP; e++) acc[e] = 0.f;
    for (int h0 = 0; h0 < H; h0 += 64) {
        float xv = xr[h0 + lane];
#pragma unroll
        for (int e = 0; e < NEXP; e++) acc[e] += xv * gw[e * H + h0 + lane];
    }
#pragma unroll
    for (int e = 0; e < NEXP; e++) {
#pragma unroll
        for (int off = 32; off > 0; off >>= 1) acc[e] += __shfl_xor(acc[e], off);
    }
    if (lane == 0) {
        float m = acc[0];
#pragma unroll
        for (int e = 1; e < NEXP; e++) m = fmaxf(m, acc[e]);
        float p[NEXP]; float z = 0.f;
#pragma unroll
        for (int e = 0; e < NEXP; e++) { p[e] = expf(acc[e] - m); z += p[e]; }
        float inv = 1.f / z;
#pragma unroll
        for (int e = 0; e < NEXP; e++) p[e] *= inv;
        int i0 = 0; float v0 = p[0];
#pragma unroll
        for (int e = 1; e < NEXP; e++) if (p[e] > v0) { v0 = p[e]; i0 = e; }
        int i1 = -1; float v1 = -1.f;
#pragma unroll
        for (int e = 0; e < NEXP; e++) if (e != i0 && p[e] > v1) { v1 = p[e]; i1 = e; }
        float s = 1.f / (v0 + v1 + 1e-8f);
        tk_e[t * 2 + 0] = i0; tk_w[t * 2 + 0] = v0 * s;
        tk_e[t * 2 + 1] = i1; tk_w[t * 2 + 1] = v1 * s;
        atomicAdd(&counts[i0], 1);
        atomicAdd(&counts[i1], 1);
    }
}

// ---------------- scan ----------------
__global__ void scan_fill_kernel(const int* __restrict__ counts, int* __restrict__ cursors,
                                 int* __restrict__ pad_off, int* __restrict__ rows_token,
                                 float* __restrict__ rows_weight, int N) {
    __shared__ int s_total;
    if (threadIdx.x == 0) {
        int off = 0;
        for (int e = 0; e < NEXP; e++) {
            pad_off[e] = off;
            cursors[e] = off;
            off += (counts[e] + 127) & ~127;
        }
        pad_off[NEXP] = off;
        s_total = off;
    }
    __syncthreads();
    int total = s_total;
    for (int r = threadIdx.x; r < 2 * N; r += blockDim.x) {
        rows_token[r] = r & (N - 1);
        rows_weight[r] = 0.5f;
    }
    for (int r = threadIdx.x; r < total; r += blockDim.x) {
        rows_token[2 * N + r] = 0;
        rows_weight[2 * N + r] = 0.f;
    }
}

// ---------------- scatter ----------------
__global__ void scatter_kernel(const int* __restrict__ tk_e, const float* __restrict__ tk_w,
                               int* __restrict__ cursors, int* __restrict__ rows_token,
                               float* __restrict__ rows_weight, int N) {
    int i = blockIdx.x * blockDim.x + threadIdx.x;
    if (i >= N * TOPK) return;
    int e = tk_e[i];
    int pos = atomicAdd(&cursors[e], 1);
    rows_token[2 * N + pos] = i >> 1;
    rows_weight[2 * N + pos] = tk_w[i];
}

// ================ bf16 transposed-weight path ================
// phase A: P = silu(X*Wg) * (X*Wu); WgT/WuT are bf16 [mat][I][H] (k=H contiguous)
// BM=128, BN=64, BK=32; 4 waves 2x2 (64m x 32n); dbuf LDS + reg prefetch
__global__ __launch_bounds__(256) void phaseA_t_kernel(
        const bf16* __restrict__ xb, const bf16* __restrict__ WgT, const bf16* __restrict__ WuT,
        const int* __restrict__ pad_off, const int* __restrict__ rows_token,
        bf16* __restrict__ P, int N, int ic0, int ichunk) {
    int mtile = swizzle_mtile(blockIdx.x, gridDim.x);
    int ntile = blockIdx.y;
    int sh_tiles = (2 * N) / 128;
    int rowbase; const bf16* gptr; const bf16* uptr;
    if (mtile < sh_tiles) {
        rowbase = mtile * 128;
        int s = rowbase / N;
        gptr = WgT + (size_t)s * MATEL;
        uptr = WuT + (size_t)s * MATEL;
    } else {
        int rm = (mtile - sh_tiles) * 128;
        if (rm >= pad_off[NEXP]) return;
        int e = NEXP - 1;
        for (int q = 0; q < NEXP; q++) { if (rm < pad_off[q + 1]) { e = q; break; } }
        rowbase = 2 * N + rm;
        gptr = WgT + (size_t)(2 + e) * MATEL;
        uptr = WuT + (size_t)(2 + e) * MATEL;
    }
    int icol0 = ic0 + ntile * 64;
    int pcol0 = ntile * 64;

    __shared__ bf16 As[2][128][40];
    __shared__ bf16 Bgs[2][64][40];
    __shared__ bf16 Bus[2][64][40];
    __shared__ int sTok[128];

    int tid = threadIdx.x;
    if (tid < 128) sTok[tid] = rows_token[rowbase + tid];
    __syncthreads();

    f32x4 accG[4][2], accU[4][2];
#pragma unroll
    for (int i = 0; i < 4; i++)
#pragma unroll
        for (int j = 0; j < 2; j++) {
            accG[i][j] = (f32x4){0.f, 0.f, 0.f, 0.f};
            accU[i][j] = (f32x4){0.f, 0.f, 0.f, 0.f};
        }

    int ar = tid >> 1, ah = tid & 1;
    const bf16* arow = xb + (size_t)sTok[ar] * H + ah * 16;
    // B staging: 4 lanes per n-row cover the 32-k extent
    int bn = tid >> 2, bkq = tid & 3;
    const bf16* gb = gptr + (size_t)(icol0 + bn) * H + bkq * 8;
    const bf16* ub = uptr + (size_t)(icol0 + bn) * H + bkq * 8;

    int lane = tid & 63, w = tid >> 6;
    int wm = (w & 1) * 64, wn = (w >> 1) * 32;
    int fr = lane & 15, fq = (lane >> 4) * 8;

    bf16x8 rA0, rA1, rG, rU;

#define PAT_LOADK(kk)                                                         \
    {                                                                         \
        rA0 = *(const bf16x8*)(arow + (kk));                                  \
        rA1 = *(const bf16x8*)(arow + (kk) + 8);                              \
        rG = *(const bf16x8*)(gb + (kk));                                     \
        rU = *(const bf16x8*)(ub + (kk));                                     \
    }
#define PAT_STORE(buf)                                                        \
    {                                                                         \
        *(bf16x8*)&As[buf][ar][ah * 16] = rA0;                                \
        *(bf16x8*)&As[buf][ar][ah * 16 + 8] = rA1;                            \
        *(bf16x8*)&Bgs[buf][bn][bkq * 8] = rG;                                \
        *(bf16x8*)&Bus[buf][bn][bkq * 8] = rU;                                \
    }

    PAT_LOADK(0);
    PAT_STORE(0);
    __syncthreads();

#pragma unroll
    for (int kb = 0; kb < 24; kb++) {
        if (kb < 23) PAT_LOADK((kb + 1) * 32);
        int cur = kb & 1;
        bf16x8 a[4], bg[2], bu[2];
#pragma unroll
        for (int mi = 0; mi < 4; mi++) a[mi] = *(const bf16x8*)&As[cur][wm + mi * 16 + fr][fq];
#pragma unroll
        for (int ni = 0; ni < 2; ni++) {
            bg[ni] = *(const bf16x8*)&Bgs[cur][wn + ni * 16 + fr][fq];
            bu[ni] = *(const bf16x8*)&Bus[cur][wn + ni * 16 + fr][fq];
        }
#pragma unroll
        for (int mi = 0; mi < 4; mi++)
#pragma unroll
            for (int ni = 0; ni < 2; ni++) {
                accG[mi][ni] = __builtin_amdgcn_mfma_f32_16x16x32_bf16(a[mi], bg[ni], accG[mi][ni], 0, 0, 0);
                accU[mi][ni] = __builtin_amdgcn_mfma_f32_16x16x32_bf16(a[mi], bu[ni], accU[mi][ni], 0, 0, 0);
            }
        if (kb < 23) {
            PAT_STORE(cur ^ 1);
            __syncthreads();
        }
    }

    int cq = lane >> 4;
#pragma unroll
    for (int mi = 0; mi < 4; mi++)
#pragma unroll
        for (int ni = 0; ni < 2; ni++) {
            int n = wn + ni * 16 + fr;
#pragma unroll
            for (int rr = 0; rr < 4; rr++) {
                int m = wm + mi * 16 + cq * 4 + rr;
                float g = accG[mi][ni][rr];
                float u = accU[mi][ni][rr];
                float pv = (g / (1.f + __expf(-g))) * u;
                P[(size_t)(rowbase + m) * ichunk + pcol0 + n] = (bf16)pv;
            }
        }
}

// phase B: out[token] += w * (P @ Wd); WdT is bf16 [mat][H][I] (k=I contiguous)
// BM=128, BN=128, BK=32; 4 waves 2x2 (64m x 64n); dbuf LDS + reg prefetch.
// K-split over blockIdx.z: each block reduces KSEG of the ichunk, partials land in
// the atomicAdd epilogue -> grid is z x bigger, fixes the 11% occupancy starvation.
__global__ __launch_bounds__(256) void phaseB_t_kernel(
        const bf16* __restrict__ P, const bf16* __restrict__ WdT,
        const int* __restrict__ pad_off, const int* __restrict__ rows_token,
        const float* __restrict__ rows_weight, float* __restrict__ out,
        int N, int ic0, int ichunk, int KSEG) {
    int mtile = swizzle_mtile(blockIdx.x, gridDim.x);
    int ntile = blockIdx.y;
    int kseg0 = blockIdx.z * KSEG;
    int sh_tiles = (2 * N) / 128;
    int rowbase; const bf16* dptr;
    if (mtile < sh_tiles) {
        rowbase = mtile * 128;
        int s = rowbase / N;
        dptr = WdT + (size_t)s * MATEL;
    } else {
        int rm = (mtile - sh_tiles) * 128;
        if (rm >= pad_off[NEXP]) return;
        int e = NEXP - 1;
        for (int q = 0; q < NEXP; q++) { if (rm < pad_off[q + 1]) { e = q; break; } }
        rowbase = 2 * N + rm;
        dptr = WdT + (size_t)(2 + e) * MATEL;
    }
    int h0 = ntile * 128;

    __shared__ bf16 As[2][128][40];
    __shared__ bf16 Bs[2][128][40];
    __shared__ int sTok[128];
    __shared__ float sW[128];

    int tid = threadIdx.x;
    if (tid < 128) {
        sTok[tid] = rows_token[rowbase + tid];
        sW[tid] = rows_weight[rowbase + tid];
    }
    __syncthreads();

    f32x4 acc[4][4];
#pragma unroll
    for (int i = 0; i < 4; i++)
#pragma unroll
        for (int j = 0; j < 4; j++) acc[i][j] = (f32x4){0.f, 0.f, 0.f, 0.f};

    int ar = tid >> 1, ah = tid & 1;
    const bf16* arow = P + (size_t)(rowbase + ar) * ichunk + kseg0 + ah * 16;
    // B staging: 2 lanes per n-row cover the 32-k extent (2 x 32B)
    int bn = tid >> 1, bkh = tid & 1;
    const bf16* db = dptr + (size_t)(h0 + bn) * I_DIM + ic0 + kseg0 + bkh * 16;

    int lane = tid & 63, w = tid >> 6;
    int wm = (w & 1) * 64, wn = (w >> 1) * 64;
    int fr = lane & 15, fq = (lane >> 4) * 8;

    bf16x8 rA0, rA1, rB0, rB1;

#define PBT_LOADK(kk)                                                         \
    {                                                                         \
        rA0 = *(const bf16x8*)(arow + (kk));                                  \
        rA1 = *(const bf16x8*)(arow + (kk) + 8);                              \
        rB0 = *(const bf16x8*)(db + (kk));                                    \
        rB1 = *(const bf16x8*)(db + (kk) + 8);                                \
    }
#define PBT_STORE(buf)                                                        \
    {                                                                         \
        *(bf16x8*)&As[buf][ar][ah * 16] = rA0;                                \
        *(bf16x8*)&As[buf][ar][ah * 16 + 8] = rA1;                            \
        *(bf16x8*)&Bs[buf][bn][bkh * 16] = rB0;                               \
        *(bf16x8*)&Bs[buf][bn][bkh * 16 + 8] = rB1;                           \
    }

    PBT_LOADK(0);
    PBT_STORE(0);
    __syncthreads();

    int KB = KSEG >> 5;
    for (int kb = 0; kb < KB; kb++) {
        if (kb + 1 < KB) PBT_LOADK((kb + 1) * 32);
        int cur = kb & 1;
        bf16x8 a[4], b[4];
#pragma unroll
        for (int mi = 0; mi < 4; mi++) a[mi] = *(const bf16x8*)&As[cur][wm + mi * 16 + fr][fq];
#pragma unroll
        for (int ni = 0; ni < 4; ni++) b[ni] = *(const bf16x8*)&Bs[cur][wn + ni * 16 + fr][fq];
#pragma unroll
        for (int mi = 0; mi < 4; mi++)
#pragma unroll
            for (int ni = 0; ni < 4; ni++)
                acc[mi][ni] = __builtin_amdgcn_mfma_f32_16x16x32_bf16(a[mi], b[ni], acc[mi][ni], 0, 0, 0);
        if (kb + 1 < KB) {
            PBT_STORE(cur ^ 1);
            __syncthreads();
        }
    }

    int cq = lane >> 4;
#pragma unroll
    for (int mi = 0; mi < 4; mi++)
#pragma unroll
        for (int ni = 0; ni < 4; ni++) {
            int n = wn + ni * 16 + fr;
#pragma unroll
            for (int rr = 0; rr < 4; rr++) {
                int m = wm + mi * 16 + cq * 4 + rr;
                atomicAdd(&out[(size_t)sTok[m] * H + h0 + n], sW[m] * acc[mi][ni][rr]);
            }
        }
}

// ================ OLD PATH (fallback when ws too small for bf16 weights) ================
__global__ __launch_bounds__(256) void phaseA_kernel(
        const bf16* __restrict__ xb, const float* __restrict__ swg, const float* __restrict__ swu,
        const float* __restrict__ wg, const float* __restrict__ wu,
        const int* __restrict__ pad_off, const int* __restrict__ rows_token,
        bf16* __restrict__ P, int N, int ic0, int ichunk) {
    int mtile = swizzle_mtile(blockIdx.x, gridDim.x);
    int ntile = blockIdx.y;
    int sh_tiles = (2 * N) / 128;
    int rowbase; const float* gptr; const float* uptr;
    if (mtile < sh_tiles) {
        rowbase = mtile * 128;
        int s = rowbase / N;
        gptr = swg + (size_t)s * H * I_DIM;
        uptr = swu + (size_t)s * H * I_DIM;
    } else {
        int rm = (mtile - sh_tiles) * 128;
        if (rm >= pad_off[NEXP]) return;
        int e = NEXP - 1;
        for (int q = 0; q < NEXP; q++) { if (rm < pad_off[q + 1]) { e = q; break; } }
        rowbase = 2 * N + rm;
        gptr = wg + (size_t)e * H * I_DIM;
        uptr = wu + (size_t)e * H * I_DIM;
    }
    int icol0 = ic0 + ntile * 64;
    int pcol0 = ntile * 64;

    __shared__ bf16 As[2][128][40];
    __shared__ bf16 Bgs[2][64][40];
    __shared__ bf16 Bus[2][64][40];
    __shared__ int sTok[128];

    int tid = threadIdx.x;
    if (tid < 128) sTok[tid] = rows_token[rowbase + tid];
    __syncthreads();

    f32x4 accG[4][2], accU[4][2];
#pragma unroll
    for (int i = 0; i < 4; i++)
#pragma unroll
        for (int j = 0; j < 2; j++) {
            accG[i][j] = (f32x4){0.f, 0.f, 0.f, 0.f};
            accU[i][j] = (f32x4){0.f, 0.f, 0.f, 0.f};
        }

    int ar = tid >> 1, ah = tid & 1;
    const bf16* arow = xb + (size_t)sTok[ar] * H + ah * 16;
    int bn = tid & 63, bkq = tid >> 6;
    const float* gbase = gptr + icol0 + bn;
    const float* ubase = uptr + icol0 + bn;

    int lane = tid & 63, w = tid >> 6;
    int wm = (w & 1) * 64, wn = (w >> 1) * 32;
    int fr = lane & 15, fq = (lane >> 4) * 8;

    bf16x8 rA0, rA1;
    float gv[8], uv[8];

#define PA_LOADK(kk)                                                          \
    {                                                                         \
        rA0 = *(const bf16x8*)(arow + (kk));                                  \
        rA1 = *(const bf16x8*)(arow + (kk) + 8);                              \
        _Pragma("unroll")                                                     \
        for (int j = 0; j < 8; j++) {                                         \
            gv[j] = gbase[(size_t)((kk) + bkq * 8 + j) * I_DIM];              \
            uv[j] = ubase[(size_t)((kk) + bkq * 8 + j) * I_DIM];              \
        }                                                                     \
    }
#define PA_STORE(buf)                                                         \
    {                                                                         \
        *(bf16x8*)&As[buf][ar][ah * 16] = rA0;                                \
        *(bf16x8*)&As[buf][ar][ah * 16 + 8] = rA1;                            \
        bf16x8 pg, pu;                                                        \
        _Pragma("unroll")                                                     \
        for (int j = 0; j < 8; j++) { pg[j] = (bf16)gv[j]; pu[j] = (bf16)uv[j]; } \
        *(bf16x8*)&Bgs[buf][bn][bkq * 8] = pg;                                \
        *(bf16x8*)&Bus[buf][bn][bkq * 8] = pu;                                \
    }

    PA_LOADK(0);
    PA_STORE(0);
    __syncthreads();

#pragma unroll
    for (int kb = 0; kb < 24; kb++) {
        if (kb < 23) PA_LOADK((kb + 1) * 32);
        int cur = kb & 1;
        bf16x8 a[4], bg[2], bu[2];
#pragma unroll
        for (int mi = 0; mi < 4; mi++) a[mi] = *(const bf16x8*)&As[cur][wm + mi * 16 + fr][fq];
#pragma unroll
        for (int ni = 0; ni < 2; ni++) {
            bg[ni] = *(const bf16x8*)&Bgs[cur][wn + ni * 16 + fr][fq];
            bu[ni] = *(const bf16x8*)&Bus[cur][wn + ni * 16 + fr][fq];
        }
#pragma unroll
        for (int mi = 0; mi < 4; mi++)
#pragma unroll
            for (int ni = 0; ni < 2; ni++) {
                accG[mi][ni] = __builtin_amdgcn_mfma_f32_16x16x32_bf16(a[mi], bg[ni], accG[mi][ni], 0, 0, 0);
                accU[mi][ni] = __builtin_amdgcn_mfma_f32_16x16x32_bf16(a[mi], bu[ni], accU[mi][ni], 0, 0, 0);
            }
        if (kb < 23) {
            PA_STORE(cur ^ 1);
            __syncthreads();
        }
    }

    int cq = lane >> 4;
#pragma unroll
    for (int mi = 0; mi < 4; mi++)
#pragma unroll
        for (int ni = 0; ni < 2; ni++) {
            int n = wn + ni * 16 + fr;
#pragma unroll
            for (int rr = 0; rr < 4; rr++) {
                int m = wm + mi * 16 + cq * 4 + rr;
                float g = accG[mi][ni][rr];
                float u = accU[mi][ni][rr];
                float pv = (g / (1.f + __expf(-g))) * u;
                P[(size_t)(rowbase + m) * ichunk + pcol0 + n] = (bf16)pv;
            }
        }
}

__global__ __launch_bounds__(256) void phaseB_kernel(
        const bf16* __restrict__ P, const float* __restrict__ swd, const float* __restrict__ wd,
        const int* __restrict__ pad_off, const int* __restrict__ rows_token,
        const float* __restrict__ rows_weight, float* __restrict__ out,
        int N, int ic0, int ichunk) {
    int mtile = swizzle_mtile(blockIdx.x, gridDim.x);
    int ntile = blockIdx.y;
    int sh_tiles = (2 * N) / 128;
    int rowbase; const float* dptr;
    if (mtile < sh_tiles) {
        rowbase = mtile * 128;
        int s = rowbase / N;
        dptr = swd + (size_t)s * I_DIM * H;
    } else {
        int rm = (mtile - sh_tiles) * 128;
        if (rm >= pad_off[NEXP]) return;
        int e = NEXP - 1;
        for (int q = 0; q < NEXP; q++) { if (rm < pad_off[q + 1]) { e = q; break; } }
        rowbase = 2 * N + rm;
        dptr = wd + (size_t)e * I_DIM * H;
    }
    int h0 = ntile * 128;

    __shared__ bf16 As[2][128][40];
    __shared__ bf16 Bs[2][128][40];
    __shared__ int sTok[128];
    __shared__ float sW[128];

    int tid = threadIdx.x;
    if (tid < 128) {
        sTok[tid] = rows_token[rowbase + tid];
        sW[tid] = rows_weight[rowbase + tid];
    }
    __syncthreads();

    f32x4 acc[4][4];
#pragma unroll
    for (int i = 0; i < 4; i++)
#pragma unroll
        for (int j = 0; j < 4; j++) acc[i][j] = (f32x4){0.f, 0.f, 0.f, 0.f};

    int ar = tid >> 1, ah = tid & 1;
    const bf16* arow = P + (size_t)(rowbase + ar) * ichunk + ah * 16;
    int bcol = tid & 127, bko = (tid >> 7) * 16;
    const float* dbase = dptr + (size_t)ic0 * H + h0 + bcol;

    int lane = tid & 63, w = tid >> 6;
    int wm = (w & 1) * 64, wn = (w >> 1) * 64;
    int fr = lane & 15, fq = (lane >> 4) * 8;

    bf16x8 rA0, rA1;
    float dv[16];

#define PB_LOADK(kk)                                                          \
    {                                                                         \
        rA0 = *(const bf16x8*)(arow + (kk));                                  \
        rA1 = *(const bf16x8*)(arow + (kk) + 8);                              \
        _Pragma("unroll")                                                     \
        for (int j = 0; j < 16; j++)                                          \
            dv[j] = dbase[(size_t)((kk) + bko + j) * H];                      \
    }
#define PB_STORE(buf)                                                         \
    {                                                                         \
        *(bf16x8*)&As[buf][ar][ah * 16] = rA0;                                \
        *(bf16x8*)&As[buf][ar][ah * 16 + 8] = rA1;                            \
        bf16x8 p0, p1;                                                        \
        _Pragma("unroll")                                                     \
        for (int j = 0; j < 8; j++) { p0[j] = (bf16)dv[j]; p1[j] = (bf16)dv[8 + j]; } \
        *(bf16x8*)&Bs[buf][bcol][bko] = p0;                                   \
        *(bf16x8*)&Bs[buf][bcol][bko + 8] = p1;                               \
    }

    PB_LOADK(0);
    PB_STORE(0);
    __syncthreads();

    int KB = ichunk >> 5;
    for (int kb = 0; kb < KB; kb++) {
        if (kb + 1 < KB) PB_LOADK((kb + 1) * 32);
        int cur = kb & 1;
        bf16x8 a[4], b[4];
#pragma unroll
        for (int mi = 0; mi < 4; mi++) a[mi] = *(const bf16x8*)&As[cur][wm + mi * 16 + fr][fq];
#pragma unroll
        for (int ni = 0; ni < 4; ni++) b[ni] = *(const bf16x8*)&Bs[cur][wn + ni * 16 + fr][fq];
#pragma unroll
        for (int mi = 0; mi < 4; mi++)
#pragma unroll
            for (int ni = 0; ni < 4; ni++)
                acc[mi][ni] = __builtin_amdgcn_mfma_f32_16x16x32_bf16(a[mi], b[ni], acc[mi][ni], 0, 0, 0);
        if (kb + 1 < KB) {
            PB_STORE(cur ^ 1);
            __syncthreads();
        }
    }

    int cq = lane >> 4;
#pragma unroll
    for (int mi = 0; mi < 4; mi++)
#pragma unroll
        for (int ni = 0; ni < 4; ni++) {
            int n = wn + ni * 16 + fr;
#pragma unroll
            for (int rr = 0; rr < 4; rr++) {
                int m = wm + mi * 16 + cq * 4 + rr;
                atomicAdd(&out[(size_t)sTok[m] * H + h0 + n], sW[m] * acc[mi][ni][rr]);
            }
        }
}

// ---------------- launch ----------------
extern "C" void kernel_launch(void* const* d_in, const int* in_sizes, int n_in,
                              void* d_out, int out_size, void* d_ws, size_t ws_size,
                              hipStream_t stream) {
    const float* x   = (const float*)d_in[0];
    const float* gw  = (const float*)d_in[1];
    const float* swg = (const float*)d_in[2];
    const float* swu = (const float*)d_in[3];
    const float* swd = (const float*)d_in[4];
    const float* wg  = (const float*)d_in[5];
    const float* wu  = (const float*)d_in[6];
    const float* wd  = (const float*)d_in[7];
    float* out = (float*)d_out;

    int N = in_sizes[0] / H;                       // 2048
    int ROWCAP = 2 * N + N * TOPK + NEXP * 128;    // 10240

    int* wsi = (int*)d_ws;
    int* counts     = wsi + 0;
    int* cursors    = wsi + 16;
    int* pad_off    = wsi + 32;
    int* tk_e       = wsi + 64;
    float* tk_w     = (float*)(wsi + 64 + 2 * N);
    int* rows_token = wsi + 64 + 4 * N;
    float* rows_weight = (float*)(wsi + 64 + 4 * N + ROWCAP);

    size_t xb_off = 131072;
    bf16* xb = (bf16*)((char*)d_ws + xb_off);
    size_t pbase = xb_off + (size_t)N * H * 2;

    const int cand[10] = {3072, 1536, 1024, 768, 512, 384, 256, 192, 128, 64};

    // New path: bf16 transposed weights (18 mats per type) + P buffer after them.
    size_t WB = 18 * MATEL * 2;                    // bytes per weight type
    size_t wt_off = pbase;                         // 16B aligned
    size_t p2base = wt_off + 3 * WB;
    int ichunk2 = 0;
    for (int i = 0; i < 10; i++) {
        if (p2base + (size_t)ROWCAP * cand[i] * 2 <= ws_size) { ichunk2 = cand[i]; break; }
    }

    hipMemsetAsync(d_out, 0, (size_t)out_size * sizeof(float), stream);
    hipMemsetAsync(d_ws, 0, 256, stream);

    cvt_x_kernel<<<(N * H) / 2048, 256, 0, stream>>>(x, xb, N * H);
    router_kernel<<<(N + 3) / 4, 256, 0, stream>>>(x, gw, tk_e, tk_w, counts, N);
    scan_fill_kernel<<<1, 256, 0, stream>>>(counts, cursors, pad_off, rows_token, rows_weight, N);
    scatter_kernel<<<(N * TOPK + 255) / 256, 256, 0, stream>>>(tk_e, tk_w, cursors, rows_token, rows_weight, N);

    int sh_tiles = (2 * N) / 128;                  // 32
    int rt_tiles = (N * TOPK + NEXP * 128) / 128;  // 48

    if (ichunk2 > 0) {
        // ---- bf16 transposed-weight path ----
        bf16* WgT = (bf16*)((char*)d_ws + wt_off);
        bf16* WuT = WgT + 18 * MATEL;
        bf16* WdT = WuT + 18 * MATEL;
        bf16* P = (bf16*)((char*)d_ws + p2base);
        int ichunk = ichunk2;

        // Wg/Wu: [H][I] -> [I][H]; Wd: [I][H] -> [H][I]. 2 dispatches total.
        transpose_gu_kernel<<<dim3(I_DIM / 64, H / 64, 36), 256, 0, stream>>>(swg, wg, swu, wu, WgT, WuT);
        transpose_d_kernel<<<dim3(H / 64, I_DIM / 64, 18), 256, 0, stream>>>(swd, wd, WdT);

        // K-split segment for phaseB: first divisor < ichunk among {768,512,384,256}
        int KSEG = ichunk;
        const int segc[4] = {768, 512, 384, 256};
        for (int i = 0; i < 4; i++) {
            if (ichunk > segc[i] && ichunk % segc[i] == 0) { KSEG = segc[i]; break; }
        }

        for (int ic0 = 0; ic0 < I_DIM; ic0 += ichunk) {
            dim3 gA(sh_tiles + rt_tiles, ichunk / 64);
            phaseA_t_kernel<<<gA, dim3(256), 0, stream>>>(xb, WgT, WuT, pad_off, rows_token, P, N, ic0, ichunk);
            dim3 gB(sh_tiles + rt_tiles, H / 128, ichunk / KSEG);
            phaseB_t_kernel<<<gB, dim3(256), 0, stream>>>(P, WdT, pad_off, rows_token, rows_weight, out, N, ic0, ichunk, KSEG);
        }
    } else {
        // ---- fallback: f32-weight path ----
        int ichunk = 64;
        for (int i = 0; i < 10; i++) {
            if (pbase + (size_t)ROWCAP * cand[i] * 2 <= ws_size) { ichunk = cand[i]; break; }
        }
        bf16* P = (bf16*)((char*)d_ws + pbase);
        for (int ic0 = 0; ic0 < I_DIM; ic0 += ichunk) {
            dim3 gA(sh_tiles + rt_tiles, ichunk / 64);
            phaseA_kernel<<<gA, dim3(256), 0, stream>>>(xb, swg, swu, wg, wu, pad_off, rows_token, P, N, ic0, ichunk);
            dim3 gB(sh_tiles + rt_tiles, H / 128);
            phaseB_kernel<<<gB, dim3(256), 0, stream>>>(P, swd, wd, pad_off, rows_token, rows_weight, out, N, ic0, ichunk);
        }
    }
}

// Round 4
// 803.214 us; speedup vs baseline: 1.4850x; 1.4850x over previous
//
#include <hip/hip_runtime.h>
#include <hip/hip_bf16.h>

#define H 768
#define I_DIM 3072
#define NEXP 16
#define TOPK 2

typedef __bf16 bf16;
typedef __bf16 bf16x4 __attribute__((ext_vector_type(4)));
typedef __bf16 bf16x8 __attribute__((ext_vector_type(8)));
typedef float f32x4 __attribute__((ext_vector_type(4)));

#define MATEL ((size_t)I_DIM * H)

// XCD-affinity swizzle: with gridDim.x % 8 == 0, linear dispatch maps block->XCD as
// bx % 8. Remap so each XCD owns gridX/8 CONSECUTIVE m-tiles -> blocks sharing an
// expert's weight slice co-locate on one XCD's L2.
__device__ __forceinline__ int swizzle_mtile(int bx, int gx) {
    int per = gx >> 3;
    if ((per << 3) != gx) return bx;
    return (bx & 7) * per + (bx >> 3);
}

// ---------------- x -> bf16 ----------------
__global__ void cvt_x_kernel(const float* __restrict__ x, bf16* __restrict__ xb, int n) {
    int i = (blockIdx.x * blockDim.x + threadIdx.x) * 8;
    if (i >= n) return;
    f32x4 v0 = *(const f32x4*)(x + i);
    f32x4 v1 = *(const f32x4*)(x + i + 4);
    bf16x8 p;
#pragma unroll
    for (int j = 0; j < 4; j++) { p[j] = (bf16)v0[j]; p[4 + j] = (bf16)v1[j]; }
    *(bf16x8*)(xb + i) = p;
}

// ---------------- weight transpose + cvt: f32 [R][C] -> bf16 [C][R] ----------------
__device__ __forceinline__ void transpose_tile(const float* __restrict__ ip,
                                               bf16* __restrict__ op, int R, int C) {
    __shared__ bf16 t[64][74];
    int c0 = blockIdx.x * 64, r0 = blockIdx.y * 64;
    int tid = threadIdx.x;
    int lr = tid >> 4, lc = (tid & 15) * 4;
#pragma unroll
    for (int p = 0; p < 4; p++) {
        int r = p * 16 + lr;
        f32x4 v = *(const f32x4*)(ip + (size_t)(r0 + r) * C + (c0 + lc));
        bf16x4 b;
#pragma unroll
        for (int j = 0; j < 4; j++) b[j] = (bf16)v[j];
        *(bf16x4*)&t[r][lc] = b;
    }
    __syncthreads();
    int oc = tid >> 2, s = (tid & 3) * 16;
    bf16x8 o0, o1;
#pragma unroll
    for (int j = 0; j < 8; j++) { o0[j] = t[s + j][oc]; o1[j] = t[s + 8 + j][oc]; }
    *(bf16x8*)(op + (size_t)(c0 + oc) * R + (r0 + s)) = o0;
    *(bf16x8*)(op + (size_t)(c0 + oc) * R + (r0 + s + 8)) = o1;
}

__global__ __launch_bounds__(256) void transpose_gu_kernel(
        const float* __restrict__ swg, const float* __restrict__ wg,
        const float* __restrict__ swu, const float* __restrict__ wu,
        bf16* __restrict__ WgT, bf16* __restrict__ WuT) {
    int z = blockIdx.z;
    const float* src; bf16* dst;
    if (z < 2)       { src = swg + (size_t)z * MATEL;        dst = WgT + (size_t)z * MATEL; }
    else if (z < 18) { src = wg  + (size_t)(z - 2) * MATEL;  dst = WgT + (size_t)z * MATEL; }
    else if (z < 20) { src = swu + (size_t)(z - 18) * MATEL; dst = WuT + (size_t)(z - 18) * MATEL; }
    else             { src = wu  + (size_t)(z - 20) * MATEL; dst = WuT + (size_t)(z - 18) * MATEL; }
    transpose_tile(src, dst, H, I_DIM);
}

__global__ __launch_bounds__(256) void transpose_d_kernel(
        const float* __restrict__ swd, const float* __restrict__ wd, bf16* __restrict__ WdT) {
    int z = blockIdx.z;
    const float* src; bf16* dst;
    if (z < 2) { src = swd + (size_t)z * MATEL;       dst = WdT + (size_t)z * MATEL; }
    else       { src = wd  + (size_t)(z - 2) * MATEL; dst = WdT + (size_t)z * MATEL; }
    transpose_tile(src, dst, I_DIM, H);
}

// ---------------- router ----------------
__global__ void router_kernel(const float* __restrict__ x, const float* __restrict__ gw,
                              int* __restrict__ tk_e, float* __restrict__ tk_w,
                              int* __restrict__ counts, int N) {
    int wave = threadIdx.x >> 6;
    int lane = threadIdx.x & 63;
    int t = blockIdx.x * 4 + wave;
    if (t >= N) return;
    const float* xr = x + (size_t)t * H;
    float acc[NEXP];
#pragma unroll
    for (int e = 0; e < NEXP; e++) acc[e] = 0.f;
    for (int h0 = 0; h0 < H; h0 += 64) {
        float xv = xr[h0 + lane];
#pragma unroll
        for (int e = 0; e < NEXP; e++) acc[e] += xv * gw[e * H + h0 + lane];
    }
#pragma unroll
    for (int e = 0; e < NEXP; e++) {
#pragma unroll
        for (int off = 32; off > 0; off >>= 1) acc[e] += __shfl_xor(acc[e], off);
    }
    if (lane == 0) {
        float m = acc[0];
#pragma unroll
        for (int e = 1; e < NEXP; e++) m = fmaxf(m, acc[e]);
        float p[NEXP]; float z = 0.f;
#pragma unroll
        for (int e = 0; e < NEXP; e++) { p[e] = expf(acc[e] - m); z += p[e]; }
        float inv = 1.f / z;
#pragma unroll
        for (int e = 0; e < NEXP; e++) p[e] *= inv;
        int i0 = 0; float v0 = p[0];
#pragma unroll
        for (int e = 1; e < NEXP; e++) if (p[e] > v0) { v0 = p[e]; i0 = e; }
        int i1 = -1; float v1 = -1.f;
#pragma unroll
        for (int e = 0; e < NEXP; e++) if (e != i0 && p[e] > v1) { v1 = p[e]; i1 = e; }
        float s = 1.f / (v0 + v1 + 1e-8f);
        tk_e[t * 2 + 0] = i0; tk_w[t * 2 + 0] = v0 * s;
        tk_e[t * 2 + 1] = i1; tk_w[t * 2 + 1] = v1 * s;
        atomicAdd(&counts[i0], 1);
        atomicAdd(&counts[i1], 1);
    }
}

// ---------------- scan ----------------
__global__ void scan_fill_kernel(const int* __restrict__ counts, int* __restrict__ cursors,
                                 int* __restrict__ pad_off, int* __restrict__ rows_token,
                                 float* __restrict__ rows_weight, int N) {
    __shared__ int s_total;
    if (threadIdx.x == 0) {
        int off = 0;
        for (int e = 0; e < NEXP; e++) {
            pad_off[e] = off;
            cursors[e] = off;
            off += (counts[e] + 127) & ~127;
        }
        pad_off[NEXP] = off;
        s_total = off;
    }
    __syncthreads();
    int total = s_total;
    for (int r = threadIdx.x; r < 2 * N; r += blockDim.x) {
        rows_token[r] = r & (N - 1);
        rows_weight[r] = 0.5f;
    }
    for (int r = threadIdx.x; r < total; r += blockDim.x) {
        rows_token[2 * N + r] = 0;
        rows_weight[2 * N + r] = 0.f;
    }
}

// ---------------- scatter (also records inverse map token*2+k -> row) ----------------
__global__ void scatter_kernel(const int* __restrict__ tk_e, const float* __restrict__ tk_w,
                               int* __restrict__ cursors, int* __restrict__ rows_token,
                               float* __restrict__ rows_weight, int* __restrict__ inv_row,
                               int N) {
    int i = blockIdx.x * blockDim.x + threadIdx.x;
    if (i >= N * TOPK) return;
    int e = tk_e[i];
    int pos = atomicAdd(&cursors[e], 1);
    rows_token[2 * N + pos] = i >> 1;
    rows_weight[2 * N + pos] = tk_w[i];
    inv_row[i] = 2 * N + pos;
}

// ---------------- combine: out[t] = 0.5*(Y[t]+Y[N+t]) + w0*Y[r0] + w1*Y[r1] ----------------
__global__ __launch_bounds__(256) void combine_kernel(
        const float* __restrict__ Y, const float* __restrict__ tk_w,
        const int* __restrict__ inv_row, float* __restrict__ out, int N) {
    int idx = blockIdx.x * blockDim.x + threadIdx.x;
    if (idx >= N * (H / 4)) return;
    int t = idx / (H / 4);
    int h4 = (idx - t * (H / 4)) * 4;
    f32x4 s0 = *(const f32x4*)(Y + (size_t)t * H + h4);
    f32x4 s1 = *(const f32x4*)(Y + (size_t)(N + t) * H + h4);
    int r0 = inv_row[t * 2], r1 = inv_row[t * 2 + 1];
    float w0 = tk_w[t * 2], w1 = tk_w[t * 2 + 1];
    f32x4 a = *(const f32x4*)(Y + (size_t)r0 * H + h4);
    f32x4 b = *(const f32x4*)(Y + (size_t)r1 * H + h4);
    f32x4 r;
#pragma unroll
    for (int j = 0; j < 4; j++) r[j] = 0.5f * (s0[j] + s1[j]) + w0 * a[j] + w1 * b[j];
    *(f32x4*)(out + (size_t)t * H + h4) = r;
}

// ================ bf16 transposed-weight path ================
// Fragment-major LDS layout: tiles stored as bf16x8[k_slot][row] (row stride 16B,
// slot stride 130/66*16B). A 16-lane group's ds_read_b128 walks consecutive rows
// -> consecutive 16B -> conflict-free; kills the 1e7+ SQ_LDS_BANK_CONFLICT of the
// [row][40] layout.

// phase A: P = silu(X*Wg) * (X*Wu); WgT/WuT bf16 [mat][I][H] (k=H contiguous)
// BM=128, BN=64, BK=32; 4 waves 2x2 (64m x 32n); dbuf LDS + reg prefetch
__global__ __launch_bounds__(256) void phaseA_t_kernel(
        const bf16* __restrict__ xb, const bf16* __restrict__ WgT, const bf16* __restrict__ WuT,
        const int* __restrict__ pad_off, const int* __restrict__ rows_token,
        bf16* __restrict__ P, int N, int ic0, int ichunk) {
    int mtile = swizzle_mtile(blockIdx.x, gridDim.x);
    int ntile = blockIdx.y;
    int sh_tiles = (2 * N) / 128;
    int rowbase; const bf16* gptr; const bf16* uptr;
    if (mtile < sh_tiles) {
        rowbase = mtile * 128;
        int s = rowbase / N;
        gptr = WgT + (size_t)s * MATEL;
        uptr = WuT + (size_t)s * MATEL;
    } else {
        int rm = (mtile - sh_tiles) * 128;
        if (rm >= pad_off[NEXP]) return;
        int e = NEXP - 1;
        for (int q = 0; q < NEXP; q++) { if (rm < pad_off[q + 1]) { e = q; break; } }
        rowbase = 2 * N + rm;
        gptr = WgT + (size_t)(2 + e) * MATEL;
        uptr = WuT + (size_t)(2 + e) * MATEL;
    }
    int icol0 = ic0 + ntile * 64;
    int pcol0 = ntile * 64;

    __shared__ bf16x8 As8[2][4][130];
    __shared__ bf16x8 Bgs8[2][4][66];
    __shared__ bf16x8 Bus8[2][4][66];
    __shared__ int sTok[128];

    int tid = threadIdx.x;
    if (tid < 128) sTok[tid] = rows_token[rowbase + tid];
    __syncthreads();

    f32x4 accG[4][2], accU[4][2];
#pragma unroll
    for (int i = 0; i < 4; i++)
#pragma unroll
        for (int j = 0; j < 2; j++) {
            accG[i][j] = (f32x4){0.f, 0.f, 0.f, 0.f};
            accU[i][j] = (f32x4){0.f, 0.f, 0.f, 0.f};
        }

    int ar = tid >> 1, ah = tid & 1;
    const bf16* arow = xb + (size_t)sTok[ar] * H + ah * 16;
    int bn = tid >> 2, bkq = tid & 3;
    const bf16* gb = gptr + (size_t)(icol0 + bn) * H + bkq * 8;
    const bf16* ub = uptr + (size_t)(icol0 + bn) * H + bkq * 8;

    int lane = tid & 63, w = tid >> 6;
    int wm = (w & 1) * 64, wn = (w >> 1) * 32;
    int fr = lane & 15, lq = lane >> 4;

    bf16x8 rA0, rA1, rG, rU;

#define PAT_LOADK(kk)                                                         \
    {                                                                         \
        rA0 = *(const bf16x8*)(arow + (kk));                                  \
        rA1 = *(const bf16x8*)(arow + (kk) + 8);                              \
        rG = *(const bf16x8*)(gb + (kk));                                     \
        rU = *(const bf16x8*)(ub + (kk));                                     \
    }
#define PAT_STORE(buf)                                                        \
    {                                                                         \
        As8[buf][2 * ah][ar] = rA0;                                           \
        As8[buf][2 * ah + 1][ar] = rA1;                                       \
        Bgs8[buf][bkq][bn] = rG;                                              \
        Bus8[buf][bkq][bn] = rU;                                              \
    }

    PAT_LOADK(0);
    PAT_STORE(0);
    __syncthreads();

#pragma unroll
    for (int kb = 0; kb < 24; kb++) {
        if (kb < 23) PAT_LOADK((kb + 1) * 32);
        int cur = kb & 1;
        bf16x8 a[4], bg[2], bu[2];
#pragma unroll
        for (int mi = 0; mi < 4; mi++) a[mi] = As8[cur][lq][wm + mi * 16 + fr];
#pragma unroll
        for (int ni = 0; ni < 2; ni++) {
            bg[ni] = Bgs8[cur][lq][wn + ni * 16 + fr];
            bu[ni] = Bus8[cur][lq][wn + ni * 16 + fr];
        }
#pragma unroll
        for (int mi = 0; mi < 4; mi++)
#pragma unroll
            for (int ni = 0; ni < 2; ni++) {
                accG[mi][ni] = __builtin_amdgcn_mfma_f32_16x16x32_bf16(a[mi], bg[ni], accG[mi][ni], 0, 0, 0);
                accU[mi][ni] = __builtin_amdgcn_mfma_f32_16x16x32_bf16(a[mi], bu[ni], accU[mi][ni], 0, 0, 0);
            }
        if (kb < 23) {
            PAT_STORE(cur ^ 1);
            __syncthreads();
        }
    }

    int cq = lane >> 4;
#pragma unroll
    for (int mi = 0; mi < 4; mi++)
#pragma unroll
        for (int ni = 0; ni < 2; ni++) {
            int n = wn + ni * 16 + fr;
#pragma unroll
            for (int rr = 0; rr < 4; rr++) {
                int m = wm + mi * 16 + cq * 4 + rr;
                float g = accG[mi][ni][rr];
                float u = accU[mi][ni][rr];
                float pv = (g / (1.f + __expf(-g))) * u;
                P[(size_t)(rowbase + m) * ichunk + pcol0 + n] = (bf16)pv;
            }
        }
}

// phase B: Y[row] (+)= P[row] @ WdT[expert]; WdT bf16 [mat][H][I] (k=I contiguous)
// BM=128, BN=128, BK=32; plain stores to Y (no atomics); weight applied in combine.
__global__ __launch_bounds__(256) void phaseB_t_kernel(
        const bf16* __restrict__ P, const bf16* __restrict__ WdT,
        const int* __restrict__ pad_off, float* __restrict__ Y,
        int N, int ic0, int ichunk) {
    int mtile = swizzle_mtile(blockIdx.x, gridDim.x);
    int ntile = blockIdx.y;
    int sh_tiles = (2 * N) / 128;
    int rowbase; const bf16* dptr;
    if (mtile < sh_tiles) {
        rowbase = mtile * 128;
        int s = rowbase / N;
        dptr = WdT + (size_t)s * MATEL;
    } else {
        int rm = (mtile - sh_tiles) * 128;
        if (rm >= pad_off[NEXP]) return;
        int e = NEXP - 1;
        for (int q = 0; q < NEXP; q++) { if (rm < pad_off[q + 1]) { e = q; break; } }
        rowbase = 2 * N + rm;
        dptr = WdT + (size_t)(2 + e) * MATEL;
    }
    int h0 = ntile * 128;

    __shared__ bf16x8 As8[2][4][130];
    __shared__ bf16x8 Bs8[2][4][130];

    int tid = threadIdx.x;

    f32x4 acc[4][4];
#pragma unroll
    for (int i = 0; i < 4; i++)
#pragma unroll
        for (int j = 0; j < 4; j++) acc[i][j] = (f32x4){0.f, 0.f, 0.f, 0.f};

    int ar = tid >> 1, ah = tid & 1;
    const bf16* arow = P + (size_t)(rowbase + ar) * ichunk + ah * 16;
    int bn = tid >> 1, bkh = tid & 1;
    const bf16* db = dptr + (size_t)(h0 + bn) * I_DIM + ic0 + bkh * 16;

    int lane = tid & 63, w = tid >> 6;
    int wm = (w & 1) * 64, wn = (w >> 1) * 64;
    int fr = lane & 15, lq = lane >> 4;

    bf16x8 rA0, rA1, rB0, rB1;

#define PBT_LOADK(kk)                                                         \
    {                                                                         \
        rA0 = *(const bf16x8*)(arow + (kk));                                  \
        rA1 = *(const bf16x8*)(arow + (kk) + 8);                              \
        rB0 = *(const bf16x8*)(db + (kk));                                    \
        rB1 = *(const bf16x8*)(db + (kk) + 8);                                \
    }
#define PBT_STORE(buf)                                                        \
    {                                                                         \
        As8[buf][2 * ah][ar] = rA0;                                           \
        As8[buf][2 * ah + 1][ar] = rA1;                                       \
        Bs8[buf][2 * bkh][bn] = rB0;                                          \
        Bs8[buf][2 * bkh + 1][bn] = rB1;                                      \
    }

    PBT_LOADK(0);
    PBT_STORE(0);
    __syncthreads();

    int KB = ichunk >> 5;
    for (int kb = 0; kb < KB; kb++) {
        if (kb + 1 < KB) PBT_LOADK((kb + 1) * 32);
        int cur = kb & 1;
        bf16x8 a[4], b[4];
#pragma unroll
        for (int mi = 0; mi < 4; mi++) a[mi] = As8[cur][lq][wm + mi * 16 + fr];
#pragma unroll
        for (int ni = 0; ni < 4; ni++) b[ni] = Bs8[cur][lq][wn + ni * 16 + fr];
#pragma unroll
        for (int mi = 0; mi < 4; mi++)
#pragma unroll
            for (int ni = 0; ni < 4; ni++)
                acc[mi][ni] = __builtin_amdgcn_mfma_f32_16x16x32_bf16(a[mi], b[ni], acc[mi][ni], 0, 0, 0);
        if (kb + 1 < KB) {
            PBT_STORE(cur ^ 1);
            __syncthreads();
        }
    }

    int cq = lane >> 4;
    int first = (ic0 == 0);
#pragma unroll
    for (int mi = 0; mi < 4; mi++)
#pragma unroll
        for (int ni = 0; ni < 4; ni++) {
            int n = wn + ni * 16 + fr;
#pragma unroll
            for (int rr = 0; rr < 4; rr++) {
                int m = wm + mi * 16 + cq * 4 + rr;
                size_t yi = (size_t)(rowbase + m) * H + h0 + n;
                float v = acc[mi][ni][rr];
                if (!first) v += Y[yi];
                Y[yi] = v;
            }
        }
}

// ================ OLD PATH (fallback when ws too small for bf16 weights) ================
__global__ __launch_bounds__(256) void phaseA_kernel(
        const bf16* __restrict__ xb, const float* __restrict__ swg, const float* __restrict__ swu,
        const float* __restrict__ wg, const float* __restrict__ wu,
        const int* __restrict__ pad_off, const int* __restrict__ rows_token,
        bf16* __restrict__ P, int N, int ic0, int ichunk) {
    int mtile = swizzle_mtile(blockIdx.x, gridDim.x);
    int ntile = blockIdx.y;
    int sh_tiles = (2 * N) / 128;
    int rowbase; const float* gptr; const float* uptr;
    if (mtile < sh_tiles) {
        rowbase = mtile * 128;
        int s = rowbase / N;
        gptr = swg + (size_t)s * H * I_DIM;
        uptr = swu + (size_t)s * H * I_DIM;
    } else {
        int rm = (mtile - sh_tiles) * 128;
        if (rm >= pad_off[NEXP]) return;
        int e = NEXP - 1;
        for (int q = 0; q < NEXP; q++) { if (rm < pad_off[q + 1]) { e = q; break; } }
        rowbase = 2 * N + rm;
        gptr = wg + (size_t)e * H * I_DIM;
        uptr = wu + (size_t)e * H * I_DIM;
    }
    int icol0 = ic0 + ntile * 64;
    int pcol0 = ntile * 64;

    __shared__ bf16 As[2][128][40];
    __shared__ bf16 Bgs[2][64][40];
    __shared__ bf16 Bus[2][64][40];
    __shared__ int sTok[128];

    int tid = threadIdx.x;
    if (tid < 128) sTok[tid] = rows_token[rowbase + tid];
    __syncthreads();

    f32x4 accG[4][2], accU[4][2];
#pragma unroll
    for (int i = 0; i < 4; i++)
#pragma unroll
        for (int j = 0; j < 2; j++) {
            accG[i][j] = (f32x4){0.f, 0.f, 0.f, 0.f};
            accU[i][j] = (f32x4){0.f, 0.f, 0.f, 0.f};
        }

    int ar = tid >> 1, ah = tid & 1;
    const bf16* arow = xb + (size_t)sTok[ar] * H + ah * 16;
    int bn = tid & 63, bkq = tid >> 6;
    const float* gbase = gptr + icol0 + bn;
    const float* ubase = uptr + icol0 + bn;

    int lane = tid & 63, w = tid >> 6;
    int wm = (w & 1) * 64, wn = (w >> 1) * 32;
    int fr = lane & 15, fq = (lane >> 4) * 8;

    bf16x8 rA0, rA1;
    float gv[8], uv[8];

#define PA_LOADK(kk)                                                          \
    {                                                                         \
        rA0 = *(const bf16x8*)(arow + (kk));                                  \
        rA1 = *(const bf16x8*)(arow + (kk) + 8);                              \
        _Pragma("unroll")                                                     \
        for (int j = 0; j < 8; j++) {                                         \
            gv[j] = gbase[(size_t)((kk) + bkq * 8 + j) * I_DIM];              \
            uv[j] = ubase[(size_t)((kk) + bkq * 8 + j) * I_DIM];              \
        }                                                                     \
    }
#define PA_STORE(buf)                                                         \
    {                                                                         \
        *(bf16x8*)&As[buf][ar][ah * 16] = rA0;                                \
        *(bf16x8*)&As[buf][ar][ah * 16 + 8] = rA1;                            \
        bf16x8 pg, pu;                                                        \
        _Pragma("unroll")                                                     \
        for (int j = 0; j < 8; j++) { pg[j] = (bf16)gv[j]; pu[j] = (bf16)uv[j]; } \
        *(bf16x8*)&Bgs[buf][bn][bkq * 8] = pg;                                \
        *(bf16x8*)&Bus[buf][bn][bkq * 8] = pu;                                \
    }

    PA_LOADK(0);
    PA_STORE(0);
    __syncthreads();

#pragma unroll
    for (int kb = 0; kb < 24; kb++) {
        if (kb < 23) PA_LOADK((kb + 1) * 32);
        int cur = kb & 1;
        bf16x8 a[4], bg[2], bu[2];
#pragma unroll
        for (int mi = 0; mi < 4; mi++) a[mi] = *(const bf16x8*)&As[cur][wm + mi * 16 + fr][fq];
#pragma unroll
        for (int ni = 0; ni < 2; ni++) {
            bg[ni] = *(const bf16x8*)&Bgs[cur][wn + ni * 16 + fr][fq];
            bu[ni] = *(const bf16x8*)&Bus[cur][wn + ni * 16 + fr][fq];
        }
#pragma unroll
        for (int mi = 0; mi < 4; mi++)
#pragma unroll
            for (int ni = 0; ni < 2; ni++) {
                accG[mi][ni] = __builtin_amdgcn_mfma_f32_16x16x32_bf16(a[mi], bg[ni], accG[mi][ni], 0, 0, 0);
                accU[mi][ni] = __builtin_amdgcn_mfma_f32_16x16x32_bf16(a[mi], bu[ni], accU[mi][ni], 0, 0, 0);
            }
        if (kb < 23) {
            PA_STORE(cur ^ 1);
            __syncthreads();
        }
    }

    int cq = lane >> 4;
#pragma unroll
    for (int mi = 0; mi < 4; mi++)
#pragma unroll
        for (int ni = 0; ni < 2; ni++) {
            int n = wn + ni * 16 + fr;
#pragma unroll
            for (int rr = 0; rr < 4; rr++) {
                int m = wm + mi * 16 + cq * 4 + rr;
                float g = accG[mi][ni][rr];
                float u = accU[mi][ni][rr];
                float pv = (g / (1.f + __expf(-g))) * u;
                P[(size_t)(rowbase + m) * ichunk + pcol0 + n] = (bf16)pv;
            }
        }
}

__global__ __launch_bounds__(256) void phaseB_kernel(
        const bf16* __restrict__ P, const float* __restrict__ swd, const float* __restrict__ wd,
        const int* __restrict__ pad_off, const int* __restrict__ rows_token,
        const float* __restrict__ rows_weight, float* __restrict__ out,
        int N, int ic0, int ichunk) {
    int mtile = swizzle_mtile(blockIdx.x, gridDim.x);
    int ntile = blockIdx.y;
    int sh_tiles = (2 * N) / 128;
    int rowbase; const float* dptr;
    if (mtile < sh_tiles) {
        rowbase = mtile * 128;
        int s = rowbase / N;
        dptr = swd + (size_t)s * I_DIM * H;
    } else {
        int rm = (mtile - sh_tiles) * 128;
        if (rm >= pad_off[NEXP]) return;
        int e = NEXP - 1;
        for (int q = 0; q < NEXP; q++) { if (rm < pad_off[q + 1]) { e = q; break; } }
        rowbase = 2 * N + rm;
        dptr = wd + (size_t)e * I_DIM * H;
    }
    int h0 = ntile * 128;

    __shared__ bf16 As[2][128][40];
    __shared__ bf16 Bs[2][128][40];
    __shared__ int sTok[128];
    __shared__ float sW[128];

    int tid = threadIdx.x;
    if (tid < 128) {
        sTok[tid] = rows_token[rowbase + tid];
        sW[tid] = rows_weight[rowbase + tid];
    }
    __syncthreads();

    f32x4 acc[4][4];
#pragma unroll
    for (int i = 0; i < 4; i++)
#pragma unroll
        for (int j = 0; j < 4; j++) acc[i][j] = (f32x4){0.f, 0.f, 0.f, 0.f};

    int ar = tid >> 1, ah = tid & 1;
    const bf16* arow = P + (size_t)(rowbase + ar) * ichunk + ah * 16;
    int bcol = tid & 127, bko = (tid >> 7) * 16;
    const float* dbase = dptr + (size_t)ic0 * H + h0 + bcol;

    int lane = tid & 63, w = tid >> 6;
    int wm = (w & 1) * 64, wn = (w >> 1) * 64;
    int fr = lane & 15, fq = (lane >> 4) * 8;

    bf16x8 rA0, rA1;
    float dv[16];

#define PB_LOADK(kk)                                                          \
    {                                                                         \
        rA0 = *(const bf16x8*)(arow + (kk));                                  \
        rA1 = *(const bf16x8*)(arow + (kk) + 8);                              \
        _Pragma("unroll")                                                     \
        for (int j = 0; j < 16; j++)                                          \
            dv[j] = dbase[(size_t)((kk) + bko + j) * H];                      \
    }
#define PB_STORE(buf)                                                         \
    {                                                                         \
        *(bf16x8*)&As[buf][ar][ah * 16] = rA0;                                \
        *(bf16x8*)&As[buf][ar][ah * 16 + 8] = rA1;                            \
        bf16x8 p0, p1;                                                        \
        _Pragma("unroll")                                                     \
        for (int j = 0; j < 8; j++) { p0[j] = (bf16)dv[j]; p1[j] = (bf16)dv[8 + j]; } \
        *(bf16x8*)&Bs[buf][bcol][bko] = p0;                                   \
        *(bf16x8*)&Bs[buf][bcol][bko + 8] = p1;                               \
    }

    PB_LOADK(0);
    PB_STORE(0);
    __syncthreads();

    int KB = ichunk >> 5;
    for (int kb = 0; kb < KB; kb++) {
        if (kb + 1 < KB) PB_LOADK((kb + 1) * 32);
        int cur = kb & 1;
        bf16x8 a[4], b[4];
#pragma unroll
        for (int mi = 0; mi < 4; mi++) a[mi] = *(const bf16x8*)&As[cur][wm + mi * 16 + fr][fq];
#pragma unroll
        for (int ni = 0; ni < 4; ni++) b[ni] = *(const bf16x8*)&Bs[cur][wn + ni * 16 + fr][fq];
#pragma unroll
        for (int mi = 0; mi < 4; mi++)
#pragma unroll
            for (int ni = 0; ni < 4; ni++)
                acc[mi][ni] = __builtin_amdgcn_mfma_f32_16x16x32_bf16(a[mi], b[ni], acc[mi][ni], 0, 0, 0);
        if (kb + 1 < KB) {
            PB_STORE(cur ^ 1);
            __syncthreads();
        }
    }

    int cq = lane >> 4;
#pragma unroll
    for (int mi = 0; mi < 4; mi++)
#pragma unroll
        for (int ni = 0; ni < 4; ni++) {
            int n = wn + ni * 16 + fr;
#pragma unroll
            for (int rr = 0; rr < 4; rr++) {
                int m = wm + mi * 16 + cq * 4 + rr;
                atomicAdd(&out[(size_t)sTok[m] * H + h0 + n], sW[m] * acc[mi][ni][rr]);
            }
        }
}

// ---------------- launch ----------------
extern "C" void kernel_launch(void* const* d_in, const int* in_sizes, int n_in,
                              void* d_out, int out_size, void* d_ws, size_t ws_size,
                              hipStream_t stream) {
    const float* x   = (const float*)d_in[0];
    const float* gw  = (const float*)d_in[1];
    const float* swg = (const float*)d_in[2];
    const float* swu = (const float*)d_in[3];
    const float* swd = (const float*)d_in[4];
    const float* wg  = (const float*)d_in[5];
    const float* wu  = (const float*)d_in[6];
    const float* wd  = (const float*)d_in[7];
    float* out = (float*)d_out;

    int N = in_sizes[0] / H;                       // 2048
    int ROWCAP = 2 * N + N * TOPK + NEXP * 128;    // 10240

    int* wsi = (int*)d_ws;
    int* counts     = wsi + 0;
    int* cursors    = wsi + 16;
    int* pad_off    = wsi + 32;
    int* tk_e       = wsi + 64;
    float* tk_w     = (float*)(wsi + 64 + 2 * N);
    int* rows_token = wsi + 64 + 4 * N;
    float* rows_weight = (float*)(wsi + 64 + 4 * N + ROWCAP);
    int* inv_row    = wsi + 64 + 4 * N + 2 * ROWCAP;

    size_t xb_off = 262144;                        // header (incl. inv_row) < 256KB
    bf16* xb = (bf16*)((char*)d_ws + xb_off);
    size_t pbase = xb_off + (size_t)N * H * 2;

    const int cand[10] = {3072, 1536, 1024, 768, 512, 384, 256, 192, 128, 64};

    // New path: bf16 transposed weights + P + f32 Y (unweighted per-row results).
    size_t WB = 18 * MATEL * 2;                    // bytes per weight type
    size_t wt_off = pbase;
    size_t p2base = wt_off + 3 * WB;
    size_t ybytes = (size_t)ROWCAP * H * 4;
    int ichunk2 = 0;
    size_t ybase = 0;
    for (int i = 0; i < 10; i++) {
        size_t pb = (size_t)ROWCAP * cand[i] * 2;
        if (p2base + pb + ybytes <= ws_size) { ichunk2 = cand[i]; ybase = p2base + pb; break; }
    }

    hipMemsetAsync(d_ws, 0, 256, stream);

    cvt_x_kernel<<<(N * H) / 2048, 256, 0, stream>>>(x, xb, N * H);
    router_kernel<<<(N + 3) / 4, 256, 0, stream>>>(x, gw, tk_e, tk_w, counts, N);
    scan_fill_kernel<<<1, 256, 0, stream>>>(counts, cursors, pad_off, rows_token, rows_weight, N);
    scatter_kernel<<<(N * TOPK + 255) / 256, 256, 0, stream>>>(tk_e, tk_w, cursors, rows_token, rows_weight, inv_row, N);

    int sh_tiles = (2 * N) / 128;                  // 32
    int rt_tiles = (N * TOPK + NEXP * 128) / 128;  // 48

    if (ichunk2 > 0) {
        // ---- bf16 transposed-weight path, no atomics ----
        bf16* WgT = (bf16*)((char*)d_ws + wt_off);
        bf16* WuT = WgT + 18 * MATEL;
        bf16* WdT = WuT + 18 * MATEL;
        bf16* P = (bf16*)((char*)d_ws + p2base);
        float* Y = (float*)((char*)d_ws + ybase);
        int ichunk = ichunk2;

        transpose_gu_kernel<<<dim3(I_DIM / 64, H / 64, 36), 256, 0, stream>>>(swg, wg, swu, wu, WgT, WuT);
        transpose_d_kernel<<<dim3(H / 64, I_DIM / 64, 18), 256, 0, stream>>>(swd, wd, WdT);

        for (int ic0 = 0; ic0 < I_DIM; ic0 += ichunk) {
            dim3 gA(sh_tiles + rt_tiles, ichunk / 64);
            phaseA_t_kernel<<<gA, dim3(256), 0, stream>>>(xb, WgT, WuT, pad_off, rows_token, P, N, ic0, ichunk);
            dim3 gB(sh_tiles + rt_tiles, H / 128);
            phaseB_t_kernel<<<gB, dim3(256), 0, stream>>>(P, WdT, pad_off, Y, N, ic0, ichunk);
        }
        combine_kernel<<<(N * (H / 4) + 255) / 256, 256, 0, stream>>>(Y, tk_w, inv_row, out, N);
    } else {
        // ---- fallback: f32-weight path (atomics) ----
        hipMemsetAsync(d_out, 0, (size_t)out_size * sizeof(float), stream);
        int ichunk = 64;
        for (int i = 0; i < 10; i++) {
            if (pbase + (size_t)ROWCAP * cand[i] * 2 <= ws_size) { ichunk = cand[i]; break; }
        }
        bf16* P = (bf16*)((char*)d_ws + pbase);
        for (int ic0 = 0; ic0 < I_DIM; ic0 += ichunk) {
            dim3 gA(sh_tiles + rt_tiles, ichunk / 64);
            phaseA_kernel<<<gA, dim3(256), 0, stream>>>(xb, swg, swu, wg, wu, pad_off, rows_token, P, N, ic0, ichunk);
            dim3 gB(sh_tiles + rt_tiles, H / 128);
            phaseB_kernel<<<gB, dim3(256), 0, stream>>>(P, swd, wd, pad_off, rows_token, rows_weight, out, N, ic0, ichunk);
        }
    }
}